// Round 7
// baseline (503.879 us; speedup 1.0000x reference)
//
#include <hip/hip_runtime.h>

// 2-layer GCN via bucketed counting sort + split-K LDS aggregation.
// R7: (1) layer-1 gather split into two passes whose tables (float2 xy = 4 MB,
// float z = 2 MB) are per-XCD-L2-resident (R6: single 8 MB xd4 table -> ~50%
// L2 miss, 247 MB of gather fetch, random-BW bound at 2.4 TB/s).
// (2) nontemporal (nt) hints on all streaming loads/stores (ei, sorted,
// partials) so streams don't evict gather tables / scatter record lines.
// Edge record u32: rec = (src<<11) | (dst&2047)  (src < 2^19).
//
// Pipeline (zero global atomics; LDS atomics only):
//   A  bucket_count   : per-block LDS hist (4-way sub-hist) -> histM[bk][blkA]
//   B1 colscan        : exclusive scan of histM rows + totals
//   B2 bucketscan     : exclusive scan of totals -> bucketPtr
//   C  bucket_scatter : place recs via bucketPtr + colPrefix + LDS cursor
//   D1 deg_partial    : split-K LDS hist -> partialD[sp][node]
//   D2 dinv_xd        : deg=sum partials; dinv=rsqrt(deg+1); txy,tz = x*dinv
//   E1a agg1xy        : split-K LDS accum of txy[src] -> pxy (float2 partials)
//   E1b agg1z         : split-K LDS accum of tz[src]  -> pz  (float partials)
//   E2 z_epilogue     : sum partials + self; W1+ReLU+W2 -> z (float2, 4 MB)
//   F1 agg2_partial   : split-K LDS accum of z[src] -> p2 (float2 partials)
//   F2 out_epilogue   : sum partials + self -> out

#define SHIFT 11
#define BSZ   2048             // nodes per bucket
#define CH    8192             // edges per block in passes A/C
#define NBK_MAX 256
#define AGG_THREADS 512
#define SPLIT 4                // sub-blocks per bucket in D1/E1/F1

union F2U { float2 f2; unsigned long long u; };

__device__ __forceinline__ int ntload_i(const int* p) { return __builtin_nontemporal_load(p); }
__device__ __forceinline__ unsigned int ntload_u(const unsigned int* p) { return __builtin_nontemporal_load(p); }
__device__ __forceinline__ float ntload_f(const float* p) { return __builtin_nontemporal_load(p); }
__device__ __forceinline__ float2 ntload_f2(const float2* p) {
    F2U c; c.u = __builtin_nontemporal_load((const unsigned long long*)p); return c.f2;
}
__device__ __forceinline__ void ntstore_f(float v, float* p) { __builtin_nontemporal_store(v, p); }
__device__ __forceinline__ void ntstore_f2(float2 v, float2* p) {
    F2U c; c.f2 = v; __builtin_nontemporal_store(c.u, (unsigned long long*)p);
}

__global__ void bucket_count_kernel(const int* __restrict__ dst, int* __restrict__ histM,
                                    int E, int NBA, int NBK) {
    __shared__ int lhist[4 * NBK_MAX];
    int t = threadIdx.x;
    for (int b = t; b < 4 * NBK; b += 256) lhist[b] = 0;
    __syncthreads();
    int sub = t & 3;
    int base = blockIdx.x * CH;
#pragma unroll
    for (int k = 0; k < CH / 256; ++k) {
        int e = base + t + k * 256;
        if (e < E) atomicAdd(&lhist[((ntload_i(&dst[e]) >> SHIFT) << 2) | sub], 1);
    }
    __syncthreads();
    for (int b = t; b < NBK; b += 256)
        histM[(size_t)b * NBA + blockIdx.x] =
            lhist[4 * b] + lhist[4 * b + 1] + lhist[4 * b + 2] + lhist[4 * b + 3];
}

// Exclusive scan of one bucket's row histM[bk][0..NBA-1] in place; totals[bk]=sum.
__global__ void colscan_kernel(int* __restrict__ histM, int* __restrict__ totals,
                               int NBA) {
    __shared__ int sdata[256];
    int t = threadIdx.x;
    size_t base = (size_t)blockIdx.x * NBA;
    int v[4];
#pragma unroll
    for (int k = 0; k < 4; ++k) { int i = t * 4 + k; v[k] = (i < NBA) ? histM[base + i] : 0; }
    int s = v[0] + v[1] + v[2] + v[3];
    sdata[t] = s;
    __syncthreads();
    for (int off = 1; off < 256; off <<= 1) {
        int xv = (t >= off) ? sdata[t - off] : 0;
        __syncthreads();
        sdata[t] += xv;
        __syncthreads();
    }
    if (t == 255) totals[blockIdx.x] = sdata[255];
    int run = sdata[t] - s;
#pragma unroll
    for (int k = 0; k < 4; ++k) { int i = t * 4 + k; if (i < NBA) histM[base + i] = run; run += v[k]; }
}

// Exclusive scan of totals[NBK] -> bucketPtr; bucketPtr[NBK]=E.
__global__ void bucketscan_kernel(const int* __restrict__ totals, int* __restrict__ bucketPtr,
                                  int NBK, int E) {
    __shared__ int sdata[256];
    int t = threadIdx.x;
    int v[4];
#pragma unroll
    for (int k = 0; k < 4; ++k) { int i = t * 4 + k; v[k] = (i < NBK) ? totals[i] : 0; }
    int s = v[0] + v[1] + v[2] + v[3];
    sdata[t] = s;
    __syncthreads();
    for (int off = 1; off < 256; off <<= 1) {
        int xv = (t >= off) ? sdata[t - off] : 0;
        __syncthreads();
        sdata[t] += xv;
        __syncthreads();
    }
    int run = sdata[t] - s;
#pragma unroll
    for (int k = 0; k < 4; ++k) { int i = t * 4 + k; if (i < NBK) bucketPtr[i] = run; run += v[k]; }
    if (t == 255) bucketPtr[NBK] = E;
}

__global__ void bucket_scatter_kernel(const int* __restrict__ ei, const int* __restrict__ histM,
                                      const int* __restrict__ bucketPtr,
                                      unsigned int* __restrict__ sorted,
                                      int E, int NBA, int NBK) {
    __shared__ int cur[NBK_MAX];
    int t = threadIdx.x;
    for (int b = t; b < NBK; b += 256)
        cur[b] = bucketPtr[b] + histM[(size_t)b * NBA + blockIdx.x];
    __syncthreads();
    int base = blockIdx.x * CH;
#pragma unroll
    for (int k = 0; k < CH / 256; ++k) {
        int e = base + t + k * 256;
        if (e < E) {
            int s = ntload_i(&ei[e]);
            int d = ntload_i(&ei[E + e]);
            int pos = atomicAdd(&cur[d >> SHIFT], 1);
            sorted[pos] = ((unsigned int)s << SHIFT) | (unsigned int)(d & (BSZ - 1));
        }
    }
}

// D1: split-K per-node degree histogram -> partialD[sp][node].
__global__ void deg_partial_kernel(const unsigned int* __restrict__ sorted,
                                   const int* __restrict__ bucketPtr,
                                   int* __restrict__ partialD, int N) {
    __shared__ int lhist[BSZ];
    int t = threadIdx.x;
    int bk = blockIdx.x >> 2, sp = blockIdx.x & 3;
    for (int l = t; l < BSZ; l += AGG_THREADS) lhist[l] = 0;
    __syncthreads();
    int beg = bucketPtr[bk], end = bucketPtr[bk + 1], len = end - beg;
    int s0 = beg + (int)(((long long)len * sp) >> 2);
    int s1 = beg + (int)(((long long)len * (sp + 1)) >> 2);
    for (int j = s0 + t; j < s1; j += AGG_THREADS)
        atomicAdd(&lhist[ntload_u(&sorted[j]) & (BSZ - 1)], 1);
    __syncthreads();
    size_t base = (size_t)sp * N;
    for (int l = t; l < BSZ; l += AGG_THREADS) {
        int i = (bk << SHIFT) + l;
        if (i < N) __builtin_nontemporal_store(lhist[l], &partialD[base + i]);
    }
}

// D2: deg = sum of partials; dinv = rsqrt(deg+1); txy = (x0,x1)*dinv; tz = x2*dinv.
__global__ void dinv_xd_kernel(const int* __restrict__ partialD, const float* __restrict__ x,
                               float* __restrict__ dinv, float2* __restrict__ txy,
                               float* __restrict__ tz, int N) {
    int i = blockIdx.x * blockDim.x + threadIdx.x;
    if (i >= N) return;
    int deg = ntload_i(&partialD[i]) + ntload_i(&partialD[(size_t)N + i]) +
              ntload_i(&partialD[2 * (size_t)N + i]) + ntload_i(&partialD[3 * (size_t)N + i]);
    float di = rsqrtf((float)(deg + 1));
    dinv[i] = di;
    float x0 = x[3 * i], x1 = x[3 * i + 1], x2 = x[3 * i + 2];
    txy[i] = make_float2(x0 * di, x1 * di);
    tz[i] = x2 * di;
}

// E1a: split-K LDS accumulation of txy[src] (4 MB L2-resident table) -> pxy.
__global__ void agg1xy_kernel(const unsigned int* __restrict__ sorted,
                              const int* __restrict__ bucketPtr,
                              const float2* __restrict__ txy,
                              float2* __restrict__ pxy, int N) {
    __shared__ float a0[BSZ], a1[BSZ];
    int t = threadIdx.x;
    int bk = blockIdx.x >> 2, sp = blockIdx.x & 3;
    for (int l = t; l < BSZ; l += AGG_THREADS) { a0[l] = 0.f; a1[l] = 0.f; }
    __syncthreads();
    int beg = bucketPtr[bk], end = bucketPtr[bk + 1], len = end - beg;
    int s0 = beg + (int)(((long long)len * sp) >> 2);
    int s1 = beg + (int)(((long long)len * (sp + 1)) >> 2);
    for (int j = s0 + t; j < s1; j += AGG_THREADS) {
        unsigned int rec = ntload_u(&sorted[j]);
        int s = rec >> SHIFT;
        int ld = rec & (BSZ - 1);
        float2 v = txy[s];            // cached gather (table resident per XCD)
        atomicAdd(&a0[ld], v.x);
        atomicAdd(&a1[ld], v.y);
    }
    __syncthreads();
    size_t base = (size_t)sp * N;
    for (int l = t; l < BSZ; l += AGG_THREADS) {
        int i = (bk << SHIFT) + l;
        if (i < N) ntstore_f2(make_float2(a0[l], a1[l]), &pxy[base + i]);
    }
}

// E1b: split-K LDS accumulation of tz[src] (2 MB L2-resident table) -> pz.
__global__ void agg1z_kernel(const unsigned int* __restrict__ sorted,
                             const int* __restrict__ bucketPtr,
                             const float* __restrict__ tz,
                             float* __restrict__ pz, int N) {
    __shared__ float a2[BSZ];
    int t = threadIdx.x;
    int bk = blockIdx.x >> 2, sp = blockIdx.x & 3;
    for (int l = t; l < BSZ; l += AGG_THREADS) a2[l] = 0.f;
    __syncthreads();
    int beg = bucketPtr[bk], end = bucketPtr[bk + 1], len = end - beg;
    int s0 = beg + (int)(((long long)len * sp) >> 2);
    int s1 = beg + (int)(((long long)len * (sp + 1)) >> 2);
    for (int j = s0 + t; j < s1; j += AGG_THREADS) {
        unsigned int rec = ntload_u(&sorted[j]);
        int s = rec >> SHIFT;
        int ld = rec & (BSZ - 1);
        atomicAdd(&a2[ld], tz[s]);    // cached gather
    }
    __syncthreads();
    size_t base = (size_t)sp * N;
    for (int l = t; l < BSZ; l += AGG_THREADS) {
        int i = (bk << SHIFT) + l;
        if (i < N) ntstore_f(a2[l], &pz[base + i]);
    }
}

// E2: sum partials + self; fused W1 + ReLU + W2 -> z (float2 table, 4 MB).
__global__ void z_epilogue_kernel(const float2* __restrict__ pxy, const float* __restrict__ pz,
                                  const float2* __restrict__ txy, const float* __restrict__ tz,
                                  const float* __restrict__ dinv,
                                  const float* __restrict__ W1, const float* __restrict__ b1,
                                  const float* __restrict__ W2, float2* __restrict__ z, int N) {
    int i = blockIdx.x * blockDim.x + threadIdx.x;
    if (i >= N) return;
    float2 q0 = ntload_f2(&pxy[i]);
    float2 q1 = ntload_f2(&pxy[(size_t)N + i]);
    float2 q2 = ntload_f2(&pxy[2 * (size_t)N + i]);
    float2 q3 = ntload_f2(&pxy[3 * (size_t)N + i]);
    float r0 = ntload_f(&pz[i]) + ntload_f(&pz[(size_t)N + i]) +
               ntload_f(&pz[2 * (size_t)N + i]) + ntload_f(&pz[3 * (size_t)N + i]);
    float2 sxy = txy[i];
    float sz = tz[i];
    float di = dinv[i];
    float s0 = (q0.x + q1.x + q2.x + q3.x + sxy.x) * di;
    float s1 = (q0.y + q1.y + q2.y + q3.y + sxy.y) * di;
    float s2 = (r0 + sz) * di;
    float m0 = 0.f, m1 = 0.f;
#pragma unroll
    for (int k = 0; k < 8; ++k) {
        float h = fmaxf(s0 * W1[k] + s1 * W1[8 + k] + s2 * W1[16 + k] + b1[k], 0.0f);
        m0 += h * W2[2 * k];
        m1 += h * W2[2 * k + 1];
    }
    z[i] = make_float2(m0 * di, m1 * di);
}

// F1: split-K LDS accumulation of z[src] (4 MB L2-resident table) -> p2.
__global__ void agg2_partial_kernel(const unsigned int* __restrict__ sorted,
                                    const int* __restrict__ bucketPtr,
                                    const float2* __restrict__ z,
                                    float2* __restrict__ p2, int N) {
    __shared__ float a0[BSZ], a1[BSZ];
    int t = threadIdx.x;
    int bk = blockIdx.x >> 2, sp = blockIdx.x & 3;
    for (int l = t; l < BSZ; l += AGG_THREADS) { a0[l] = 0.f; a1[l] = 0.f; }
    __syncthreads();
    int beg = bucketPtr[bk], end = bucketPtr[bk + 1], len = end - beg;
    int s0 = beg + (int)(((long long)len * sp) >> 2);
    int s1 = beg + (int)(((long long)len * (sp + 1)) >> 2);
    for (int j = s0 + t; j < s1; j += AGG_THREADS) {
        unsigned int rec = ntload_u(&sorted[j]);
        int s = rec >> SHIFT;
        int ld = rec & (BSZ - 1);
        float2 zv = z[s];             // cached gather
        atomicAdd(&a0[ld], zv.x);
        atomicAdd(&a1[ld], zv.y);
    }
    __syncthreads();
    size_t base = (size_t)sp * N;
    for (int l = t; l < BSZ; l += AGG_THREADS) {
        int i = (bk << SHIFT) + l;
        if (i < N) ntstore_f2(make_float2(a0[l], a1[l]), &p2[base + i]);
    }
}

// F2: sum partials + self -> out.
__global__ void out_epilogue_kernel(const float2* __restrict__ p2,
                                    const float2* __restrict__ z, const float* __restrict__ dinv,
                                    const float* __restrict__ b2, float* __restrict__ out, int N) {
    int i = blockIdx.x * blockDim.x + threadIdx.x;
    if (i >= N) return;
    float2 q0 = ntload_f2(&p2[i]);
    float2 q1 = ntload_f2(&p2[(size_t)N + i]);
    float2 q2 = ntload_f2(&p2[2 * (size_t)N + i]);
    float2 q3 = ntload_f2(&p2[3 * (size_t)N + i]);
    const float2 zs = z[i];
    float di = dinv[i];
    out[(size_t)i * 2]     = di * (q0.x + q1.x + q2.x + q3.x + zs.x) + b2[0];
    out[(size_t)i * 2 + 1] = di * (q0.y + q1.y + q2.y + q3.y + zs.y) + b2[1];
}

extern "C" void kernel_launch(void* const* d_in, const int* in_sizes, int n_in,
                              void* d_out, int out_size, void* d_ws, size_t ws_size,
                              hipStream_t stream) {
    const float* x  = (const float*)d_in[0];
    const int*   ei = (const int*)d_in[1];   // [2, E] flat: src row, dst row
    const float* W1 = (const float*)d_in[2];
    const float* b1 = (const float*)d_in[3];
    const float* W2 = (const float*)d_in[4];
    const float* b2 = (const float*)d_in[5];
    float* out = (float*)d_out;

    const int N = in_sizes[0] / 3;
    const int E = in_sizes[1] / 2;
    const int NBK = (N + BSZ - 1) / BSZ;       // 245 buckets
    const int NBA = (E + CH - 1) / CH;         // 977 blocks in A/C

    // Workspace carve-up. `scratch` (32 MB) reused sequentially: partialD
    // (D1->D2), then pxy+pz (E1->E2), then p2 (F1->F2).
    char* ws = (char*)d_ws;
    size_t off = 0;
    auto alloc = [&](size_t bytes) { char* p = ws + off; off = (off + bytes + 15) & ~(size_t)15; return p; };
    int* histM           = (int*)alloc((size_t)NBK * NBA * 4);
    int* totals          = (int*)alloc((size_t)NBK * 4);
    int* bucketPtr       = (int*)alloc(((size_t)NBK + 1) * 4);
    char* scratch        = alloc((size_t)SPLIT * N * 16);
    float* dinv          = (float*)alloc((size_t)N * 4);
    float2* z            = (float2*)alloc((size_t)N * 8);
    float2* txy          = (float2*)alloc((size_t)N * 8);
    float* tz            = (float*)alloc((size_t)N * 4);
    unsigned int* sorted = (unsigned int*)alloc((size_t)E * 4);
    (void)ws_size;

    int* partialD = (int*)scratch;
    float2* pxy   = (float2*)scratch;                              // SPLIT*N*8
    float* pz     = (float*)(scratch + (size_t)SPLIT * N * 8);     // SPLIT*N*4
    float2* p2    = (float2*)scratch;                              // SPLIT*N*8

    const int nb = (N + 255) / 256;

    bucket_count_kernel<<<NBA, 256, 0, stream>>>(ei + E, histM, E, NBA, NBK);
    colscan_kernel<<<NBK, 256, 0, stream>>>(histM, totals, NBA);
    bucketscan_kernel<<<1, 256, 0, stream>>>(totals, bucketPtr, NBK, E);
    bucket_scatter_kernel<<<NBA, 256, 0, stream>>>(ei, histM, bucketPtr, sorted, E, NBA, NBK);
    deg_partial_kernel<<<NBK * SPLIT, AGG_THREADS, 0, stream>>>(sorted, bucketPtr, partialD, N);
    dinv_xd_kernel<<<nb, 256, 0, stream>>>(partialD, x, dinv, txy, tz, N);
    agg1xy_kernel<<<NBK * SPLIT, AGG_THREADS, 0, stream>>>(sorted, bucketPtr, txy, pxy, N);
    agg1z_kernel<<<NBK * SPLIT, AGG_THREADS, 0, stream>>>(sorted, bucketPtr, tz, pz, N);
    z_epilogue_kernel<<<nb, 256, 0, stream>>>(pxy, pz, txy, tz, dinv, W1, b1, W2, z, N);
    agg2_partial_kernel<<<NBK * SPLIT, AGG_THREADS, 0, stream>>>(sorted, bucketPtr, z, p2, N);
    out_epilogue_kernel<<<nb, 256, 0, stream>>>(p2, z, dinv, b2, out, N);
}

// Round 9
// 439.911 us; speedup vs baseline: 1.1454x; 1.1454x over previous
//
#include <hip/hip_runtime.h>

// 2-layer GCN via bucketed counting sort + split-K LDS aggregation.
// R8: (1) scatter/count use CH=32768 (512 thr, 245 blocks) so the number of
// concurrently-open partially-written cache lines (resident-blocks x 245
// cursors x 64B) drops ~4x below per-XCD L2 -> write merging. (2) layer-1
// aggregation re-fused to ONE pass gathering a 4 MB fp16 table (4x _Float16
// per node) that is per-XCD-L2-resident; self term recomputed in fp32 in the
// epilogue so only neighbor sums see fp16 quantization.
// Edge record u32: rec = (src<<11) | (dst&2047)  (src < 2^19).
//
// Pipeline (zero global atomics; LDS atomics only):
//   A  bucket_count   : per-block LDS hist (4-way sub-hist) -> histM[bk][blkA]
//   B1 colscan        : exclusive scan of histM rows + totals
//   B2 bucketscan     : exclusive scan of totals -> bucketPtr
//   C  bucket_scatter : place recs via bucketPtr + colPrefix + LDS cursor
//   D1 deg_partial    : split-K LDS hist -> partialD[sp][node]
//   D2 dinv_xd        : deg=sum partials; dinv=rsqrt(deg+1); th4=fp16(x*dinv)
//   E1 agg1_partial   : split-K LDS fp32 accum of th4[src] -> partial1 (float4)
//   E2 z_epilogue     : sum partials + fp32 self; W1+ReLU+W2 -> z (float2, 4MB)
//   F1 agg2_partial   : split-K LDS accum of z[src] (4MB resident) -> p2
//   F2 out_epilogue   : sum partials + self -> out

#define SHIFT 11
#define BSZ   2048             // nodes per bucket
#define CH    32768            // edges per block in passes A/C
#define AC_THREADS 512
#define NBK_MAX 256
#define AGG_THREADS 512
#define SPLIT 4                // sub-blocks per bucket in D1/E1/F1

typedef float vfloat4 __attribute__((ext_vector_type(4)));   // native vec for nt builtins

union F2U { float2 f2; unsigned long long u; };
union H4 { uint2 u; _Float16 h[4]; };

__device__ __forceinline__ int ntload_i(const int* p) { return __builtin_nontemporal_load(p); }
__device__ __forceinline__ unsigned int ntload_u(const unsigned int* p) { return __builtin_nontemporal_load(p); }
__device__ __forceinline__ float ntload_f(const float* p) { return __builtin_nontemporal_load(p); }
__device__ __forceinline__ float2 ntload_f2(const float2* p) {
    F2U c; c.u = __builtin_nontemporal_load((const unsigned long long*)p); return c.f2;
}
__device__ __forceinline__ void ntstore_f2(float2 v, float2* p) {
    F2U c; c.f2 = v; __builtin_nontemporal_store(c.u, (unsigned long long*)p);
}
__device__ __forceinline__ void ntstore_f4(float4 v, float4* p) {
    vfloat4 nv = {v.x, v.y, v.z, v.w};
    __builtin_nontemporal_store(nv, (vfloat4*)p);
}
__device__ __forceinline__ float4 ntload_f4(const float4* p) {
    vfloat4 nv = __builtin_nontemporal_load((const vfloat4*)p);
    return make_float4(nv.x, nv.y, nv.z, nv.w);
}

__global__ void bucket_count_kernel(const int* __restrict__ dst, int* __restrict__ histM,
                                    int E, int NBA, int NBK) {
    __shared__ int lhist[4 * NBK_MAX];
    int t = threadIdx.x;
    for (int b = t; b < 4 * NBK; b += AC_THREADS) lhist[b] = 0;
    __syncthreads();
    int sub = t & 3;
    int base = blockIdx.x * CH;
#pragma unroll 8
    for (int k = 0; k < CH / AC_THREADS; ++k) {
        int e = base + t + k * AC_THREADS;
        if (e < E) atomicAdd(&lhist[((ntload_i(&dst[e]) >> SHIFT) << 2) | sub], 1);
    }
    __syncthreads();
    for (int b = t; b < NBK; b += AC_THREADS)
        histM[(size_t)b * NBA + blockIdx.x] =
            lhist[4 * b] + lhist[4 * b + 1] + lhist[4 * b + 2] + lhist[4 * b + 3];
}

// Exclusive scan of one bucket's row histM[bk][0..NBA-1] in place; totals[bk]=sum.
__global__ void colscan_kernel(int* __restrict__ histM, int* __restrict__ totals,
                               int NBA) {
    __shared__ int sdata[256];
    int t = threadIdx.x;
    size_t base = (size_t)blockIdx.x * NBA;
    int v[4];
#pragma unroll
    for (int k = 0; k < 4; ++k) { int i = t * 4 + k; v[k] = (i < NBA) ? histM[base + i] : 0; }
    int s = v[0] + v[1] + v[2] + v[3];
    sdata[t] = s;
    __syncthreads();
    for (int off = 1; off < 256; off <<= 1) {
        int xv = (t >= off) ? sdata[t - off] : 0;
        __syncthreads();
        sdata[t] += xv;
        __syncthreads();
    }
    if (t == 255) totals[blockIdx.x] = sdata[255];
    int run = sdata[t] - s;
#pragma unroll
    for (int k = 0; k < 4; ++k) { int i = t * 4 + k; if (i < NBA) histM[base + i] = run; run += v[k]; }
}

// Exclusive scan of totals[NBK] -> bucketPtr; bucketPtr[NBK]=E.
__global__ void bucketscan_kernel(const int* __restrict__ totals, int* __restrict__ bucketPtr,
                                  int NBK, int E) {
    __shared__ int sdata[256];
    int t = threadIdx.x;
    int v[4];
#pragma unroll
    for (int k = 0; k < 4; ++k) { int i = t * 4 + k; v[k] = (i < NBK) ? totals[i] : 0; }
    int s = v[0] + v[1] + v[2] + v[3];
    sdata[t] = s;
    __syncthreads();
    for (int off = 1; off < 256; off <<= 1) {
        int xv = (t >= off) ? sdata[t - off] : 0;
        __syncthreads();
        sdata[t] += xv;
        __syncthreads();
    }
    int run = sdata[t] - s;
#pragma unroll
    for (int k = 0; k < 4; ++k) { int i = t * 4 + k; if (i < NBK) bucketPtr[i] = run; run += v[k]; }
    if (t == 255) bucketPtr[NBK] = E;
}

__global__ void bucket_scatter_kernel(const int* __restrict__ ei, const int* __restrict__ histM,
                                      const int* __restrict__ bucketPtr,
                                      unsigned int* __restrict__ sorted,
                                      int E, int NBA, int NBK) {
    __shared__ int cur[NBK_MAX];
    int t = threadIdx.x;
    for (int b = t; b < NBK; b += AC_THREADS)
        cur[b] = bucketPtr[b] + histM[(size_t)b * NBA + blockIdx.x];
    __syncthreads();
    int base = blockIdx.x * CH;
#pragma unroll 8
    for (int k = 0; k < CH / AC_THREADS; ++k) {
        int e = base + t + k * AC_THREADS;
        if (e < E) {
            int s = ntload_i(&ei[e]);
            int d = ntload_i(&ei[E + e]);
            int pos = atomicAdd(&cur[d >> SHIFT], 1);
            sorted[pos] = ((unsigned int)s << SHIFT) | (unsigned int)(d & (BSZ - 1));
        }
    }
}

// D1: split-K per-node degree histogram -> partialD[sp][node].
__global__ void deg_partial_kernel(const unsigned int* __restrict__ sorted,
                                   const int* __restrict__ bucketPtr,
                                   int* __restrict__ partialD, int N) {
    __shared__ int lhist[BSZ];
    int t = threadIdx.x;
    int bk = blockIdx.x >> 2, sp = blockIdx.x & 3;
    for (int l = t; l < BSZ; l += AGG_THREADS) lhist[l] = 0;
    __syncthreads();
    int beg = bucketPtr[bk], end = bucketPtr[bk + 1], len = end - beg;
    int s0 = beg + (int)(((long long)len * sp) >> 2);
    int s1 = beg + (int)(((long long)len * (sp + 1)) >> 2);
    for (int j = s0 + t; j < s1; j += AGG_THREADS)
        atomicAdd(&lhist[ntload_u(&sorted[j]) & (BSZ - 1)], 1);
    __syncthreads();
    size_t base = (size_t)sp * N;
    for (int l = t; l < BSZ; l += AGG_THREADS) {
        int i = (bk << SHIFT) + l;
        if (i < N) __builtin_nontemporal_store(lhist[l], &partialD[base + i]);
    }
}

// D2: deg = sum of partials; dinv = rsqrt(deg+1); th4 = fp16{x*dinv, pad}.
__global__ void dinv_xd_kernel(const int* __restrict__ partialD, const float* __restrict__ x,
                               float* __restrict__ dinv, uint2* __restrict__ th4, int N) {
    int i = blockIdx.x * blockDim.x + threadIdx.x;
    if (i >= N) return;
    int deg = ntload_i(&partialD[i]) + ntload_i(&partialD[(size_t)N + i]) +
              ntload_i(&partialD[2 * (size_t)N + i]) + ntload_i(&partialD[3 * (size_t)N + i]);
    float di = rsqrtf((float)(deg + 1));
    dinv[i] = di;
    float x0 = x[3 * i], x1 = x[3 * i + 1], x2 = x[3 * i + 2];
    H4 c;
    c.h[0] = (_Float16)(x0 * di);
    c.h[1] = (_Float16)(x1 * di);
    c.h[2] = (_Float16)(x2 * di);
    c.h[3] = (_Float16)0.f;
    th4[i] = c.u;
}

// E1: split-K LDS fp32 accumulation of fp16 th4[src] (4 MB resident) -> partial1.
__global__ void agg1_partial_kernel(const unsigned int* __restrict__ sorted,
                                    const int* __restrict__ bucketPtr,
                                    const uint2* __restrict__ th4,
                                    float4* __restrict__ partial1, int N) {
    __shared__ float a0[BSZ], a1[BSZ], a2[BSZ];
    int t = threadIdx.x;
    int bk = blockIdx.x >> 2, sp = blockIdx.x & 3;
    for (int l = t; l < BSZ; l += AGG_THREADS) { a0[l] = 0.f; a1[l] = 0.f; a2[l] = 0.f; }
    __syncthreads();
    int beg = bucketPtr[bk], end = bucketPtr[bk + 1], len = end - beg;
    int s0 = beg + (int)(((long long)len * sp) >> 2);
    int s1 = beg + (int)(((long long)len * (sp + 1)) >> 2);
    for (int j = s0 + t; j < s1; j += AGG_THREADS) {
        unsigned int rec = ntload_u(&sorted[j]);
        int s = rec >> SHIFT;
        int ld = rec & (BSZ - 1);
        H4 c; c.u = th4[s];           // cached 8B gather, table resident per XCD
        atomicAdd(&a0[ld], (float)c.h[0]);
        atomicAdd(&a1[ld], (float)c.h[1]);
        atomicAdd(&a2[ld], (float)c.h[2]);
    }
    __syncthreads();
    size_t base = (size_t)sp * N;
    for (int l = t; l < BSZ; l += AGG_THREADS) {
        int i = (bk << SHIFT) + l;
        if (i < N) ntstore_f4(make_float4(a0[l], a1[l], a2[l], 0.0f), &partial1[base + i]);
    }
}

// E2: sum partials + fp32 self; fused W1 + ReLU + W2 -> z (float2 table, 4 MB).
__global__ void z_epilogue_kernel(const float4* __restrict__ partial1,
                                  const float* __restrict__ x, const float* __restrict__ dinv,
                                  const float* __restrict__ W1, const float* __restrict__ b1,
                                  const float* __restrict__ W2, float2* __restrict__ z, int N) {
    int i = blockIdx.x * blockDim.x + threadIdx.x;
    if (i >= N) return;
    float4 p0 = ntload_f4(&partial1[i]);
    float4 p1 = ntload_f4(&partial1[(size_t)N + i]);
    float4 p2 = ntload_f4(&partial1[2 * (size_t)N + i]);
    float4 p3 = ntload_f4(&partial1[3 * (size_t)N + i]);
    float di = dinv[i];
    float x0 = x[3 * i], x1 = x[3 * i + 1], x2 = x[3 * i + 2];
    float s0 = (p0.x + p1.x + p2.x + p3.x + x0 * di) * di;
    float s1 = (p0.y + p1.y + p2.y + p3.y + x1 * di) * di;
    float s2 = (p0.z + p1.z + p2.z + p3.z + x2 * di) * di;
    float m0 = 0.f, m1 = 0.f;
#pragma unroll
    for (int k = 0; k < 8; ++k) {
        float h = fmaxf(s0 * W1[k] + s1 * W1[8 + k] + s2 * W1[16 + k] + b1[k], 0.0f);
        m0 += h * W2[2 * k];
        m1 += h * W2[2 * k + 1];
    }
    z[i] = make_float2(m0 * di, m1 * di);
}

// F1: split-K LDS accumulation of z[src] (4 MB resident) -> p2 (float2).
__global__ void agg2_partial_kernel(const unsigned int* __restrict__ sorted,
                                    const int* __restrict__ bucketPtr,
                                    const float2* __restrict__ z,
                                    float2* __restrict__ p2, int N) {
    __shared__ float a0[BSZ], a1[BSZ];
    int t = threadIdx.x;
    int bk = blockIdx.x >> 2, sp = blockIdx.x & 3;
    for (int l = t; l < BSZ; l += AGG_THREADS) { a0[l] = 0.f; a1[l] = 0.f; }
    __syncthreads();
    int beg = bucketPtr[bk], end = bucketPtr[bk + 1], len = end - beg;
    int s0 = beg + (int)(((long long)len * sp) >> 2);
    int s1 = beg + (int)(((long long)len * (sp + 1)) >> 2);
    for (int j = s0 + t; j < s1; j += AGG_THREADS) {
        unsigned int rec = ntload_u(&sorted[j]);
        int s = rec >> SHIFT;
        int ld = rec & (BSZ - 1);
        float2 zv = z[s];             // cached gather
        atomicAdd(&a0[ld], zv.x);
        atomicAdd(&a1[ld], zv.y);
    }
    __syncthreads();
    size_t base = (size_t)sp * N;
    for (int l = t; l < BSZ; l += AGG_THREADS) {
        int i = (bk << SHIFT) + l;
        if (i < N) ntstore_f2(make_float2(a0[l], a1[l]), &p2[base + i]);
    }
}

// F2: sum partials + self -> out.
__global__ void out_epilogue_kernel(const float2* __restrict__ p2,
                                    const float2* __restrict__ z, const float* __restrict__ dinv,
                                    const float* __restrict__ b2, float* __restrict__ out, int N) {
    int i = blockIdx.x * blockDim.x + threadIdx.x;
    if (i >= N) return;
    float2 q0 = ntload_f2(&p2[i]);
    float2 q1 = ntload_f2(&p2[(size_t)N + i]);
    float2 q2 = ntload_f2(&p2[2 * (size_t)N + i]);
    float2 q3 = ntload_f2(&p2[3 * (size_t)N + i]);
    const float2 zs = z[i];
    float di = dinv[i];
    out[(size_t)i * 2]     = di * (q0.x + q1.x + q2.x + q3.x + zs.x) + b2[0];
    out[(size_t)i * 2 + 1] = di * (q0.y + q1.y + q2.y + q3.y + zs.y) + b2[1];
}

extern "C" void kernel_launch(void* const* d_in, const int* in_sizes, int n_in,
                              void* d_out, int out_size, void* d_ws, size_t ws_size,
                              hipStream_t stream) {
    const float* x  = (const float*)d_in[0];
    const int*   ei = (const int*)d_in[1];   // [2, E] flat: src row, dst row
    const float* W1 = (const float*)d_in[2];
    const float* b1 = (const float*)d_in[3];
    const float* W2 = (const float*)d_in[4];
    const float* b2 = (const float*)d_in[5];
    float* out = (float*)d_out;

    const int N = in_sizes[0] / 3;
    const int E = in_sizes[1] / 2;
    const int NBK = (N + BSZ - 1) / BSZ;       // 245 buckets
    const int NBA = (E + CH - 1) / CH;         // 245 blocks in A/C

    // Workspace carve-up. `scratch` (32 MB) reused sequentially: partialD
    // (D1->D2), then partial1 (E1->E2), then p2 (F1->F2).
    char* ws = (char*)d_ws;
    size_t off = 0;
    auto alloc = [&](size_t bytes) { char* p = ws + off; off = (off + bytes + 15) & ~(size_t)15; return p; };
    int* histM           = (int*)alloc((size_t)NBK * NBA * 4);
    int* totals          = (int*)alloc((size_t)NBK * 4);
    int* bucketPtr       = (int*)alloc(((size_t)NBK + 1) * 4);
    char* scratch        = alloc((size_t)SPLIT * N * 16);
    float* dinv          = (float*)alloc((size_t)N * 4);
    float2* z            = (float2*)alloc((size_t)N * 8);
    uint2* th4           = (uint2*)alloc((size_t)N * 8);
    unsigned int* sorted = (unsigned int*)alloc((size_t)E * 4);
    (void)ws_size;

    int* partialD    = (int*)scratch;
    float4* partial1 = (float4*)scratch;     // SPLIT*N*16
    float2* p2       = (float2*)scratch;     // SPLIT*N*8

    const int nb = (N + 255) / 256;

    bucket_count_kernel<<<NBA, AC_THREADS, 0, stream>>>(ei + E, histM, E, NBA, NBK);
    colscan_kernel<<<NBK, 256, 0, stream>>>(histM, totals, NBA);
    bucketscan_kernel<<<1, 256, 0, stream>>>(totals, bucketPtr, NBK, E);
    bucket_scatter_kernel<<<NBA, AC_THREADS, 0, stream>>>(ei, histM, bucketPtr, sorted, E, NBA, NBK);
    deg_partial_kernel<<<NBK * SPLIT, AGG_THREADS, 0, stream>>>(sorted, bucketPtr, partialD, N);
    dinv_xd_kernel<<<nb, 256, 0, stream>>>(partialD, x, dinv, th4, N);
    agg1_partial_kernel<<<NBK * SPLIT, AGG_THREADS, 0, stream>>>(sorted, bucketPtr, th4, partial1, N);
    z_epilogue_kernel<<<nb, 256, 0, stream>>>(partial1, x, dinv, W1, b1, W2, z, N);
    agg2_partial_kernel<<<NBK * SPLIT, AGG_THREADS, 0, stream>>>(sorted, bucketPtr, z, p2, N);
    out_epilogue_kernel<<<nb, 256, 0, stream>>>(p2, z, dinv, b2, out, N);
}